// Round 3
// baseline (680.046 us; speedup 1.0000x reference)
//
#include <hip/hip_runtime.h>

// ---------------- problem constants ----------------
#define B_    16
#define M_    128
#define N_    128
#define DIN   12
#define D_    64
#define H_    128
#define MODES 16
#define NL    4
#define NPIX  262144       // B*M*N

// ---------------- vector types ----------------
typedef float  f32x2 __attribute__((ext_vector_type(2)));
typedef float  f32x4 __attribute__((ext_vector_type(4)));
typedef short  s16x8 __attribute__((ext_vector_type(8)));
typedef unsigned int u32x4 __attribute__((ext_vector_type(4)));

// ---------------- workspace layout (BYTE offsets) ----------------
#define WSB_X      0L            // [B,M,N,64] f32                67108864
#define WSB_XSX    67108864L     // [B,M,N,64] bf16 (x-axis part) 33554432
#define WSB_BF     100663296L    // fwd basis bf16 [kp=32][n=128]  8192
#define WSB_BI     100671488L    // inv basis bf16 [n=128][kp=32]  8192
#define WSB_U      100679680L    // u[4][128] f32                  2048
#define WSB_D      100681728L    // d[4] f32                       16
#define WSB_WFF    100681744L    // FF weights bf16 (3x4x8192 u16) 196608
#define WSB_WMIX   100878352L    // mix weights u32(re|im) [ax][l][k][i][o] 2097152
#define WS_NEEDED  102975504L

__device__ __forceinline__ unsigned short f2bf(float f){
    unsigned int u = __float_as_uint(f);
    u += 0x7fffu + ((u >> 16) & 1u);
    return (unsigned short)(u >> 16);
}
__device__ __forceinline__ float bf2f(unsigned short s){
    return __uint_as_float(((unsigned int)s) << 16);
}
// packed f32x2 -> bf16x2 (lo = a, hi = b), single HW instruction
__device__ __forceinline__ unsigned int cvtpk(float lo, float hi){
    unsigned int r;
    asm("v_cvt_pk_bf16_f32 %0, %1, %2" : "=v"(r) : "v"(lo), "v"(hi));
    return r;
}

// ============ init: bf16 basis tables + collapsed output head ============
__global__ void k_init(const float* __restrict__ out_w1, const float* __restrict__ out_b1,
                       const float* __restrict__ out_w2, const float* __restrict__ out_b2,
                       const float* __restrict__ fc_w2, const float* __restrict__ fc_b2,
                       float* __restrict__ ws){
    __shared__ float v_s[64];
    __shared__ float c_s;
    int t = threadIdx.x;
    if (t < 64){
        float a = 0.f;
        for (int j = 0; j < H_; j++) a += out_w1[t*H_ + j] * out_w2[j];
        v_s[t] = a;
    }
    if (t == 64){
        float a = 0.f;
        for (int j = 0; j < H_; j++) a += out_b1[j] * out_w2[j];
        c_s = a + out_b2[0];
    }
    __syncthreads();
    float* uw = (float*)((char*)ws + WSB_U);
    float* dw = (float*)((char*)ws + WSB_D);
    if (t < 128){
        for (int l = 0; l < NL; l++){
            float a = 0.f;
            for (int o = 0; o < D_; o++) a += fc_w2[(l*H_ + t)*D_ + o] * v_s[o];
            uw[l*128 + t] = a;
        }
    }
    if (t >= 128 && t < 132){
        int l = t - 128;
        float a = 0.f;
        for (int o = 0; o < D_; o++) a += fc_b2[l*D_ + o] * v_s[o];
        dw[l] = a + c_s;
    }
    const float isn = 0.08838834764831845f;  // 1/sqrt(128)
    unsigned short* bft = (unsigned short*)((char*)ws + WSB_BF);
    unsigned short* bit = (unsigned short*)((char*)ws + WSB_BI);
    for (int e = t; e < 4096; e += 256){
        { int kp = e >> 7, n = e & 127, k = kp >> 1;
          float ang = 6.283185307179586f * (float)((k*n) & 127) / 128.0f;
          bft[e] = f2bf((kp & 1) ? (-sinf(ang)*isn) : (cosf(ang)*isn)); }
        { int n = e >> 5, kp = e & 31, k = kp >> 1;
          float ang = 6.283185307179586f * (float)((k*n) & 127) / 128.0f;
          float val;
          if (kp & 1) val = (k == 0) ? 0.f : (-2.f*sinf(ang)*isn);
          else        val = ((k == 0) ? 1.f : 2.f) * cosf(ang) * isn;
          bit[e] = f2bf(val); }
    }
}

// ============ FF weights -> bf16 transposed ============
__global__ void k_wconv(const float* __restrict__ bc_w1, const float* __restrict__ fc_w1,
                        const float* __restrict__ bc_w2, float* __restrict__ ws){
    unsigned short* wb = (unsigned short*)((char*)ws + WSB_WFF);
    int e = blockIdx.x*256 + threadIdx.x;      // < 98304
    int a = e >> 15;
    int r = e & 32767;
    int l = r >> 13;
    int q = r & 8191;
    if (a == 0){
        int j = q >> 6, i = q & 63;
        wb[e] = f2bf(bc_w1[(l*D_ + i)*H_ + j]);
    } else if (a == 1){
        int j = q >> 6, i = q & 63;
        wb[e] = f2bf(fc_w1[(l*D_ + i)*H_ + j]);
    } else {
        int o = q >> 7, j = q & 127;
        wb[e] = f2bf(bc_w2[(l*H_ + j)*D_ + o]);
    }
}

// ============ mix weights -> packed bf16 u32 [ax][l][k][i][o] ============
__global__ void k_wmix(const float* __restrict__ fwy_re, const float* __restrict__ fwy_im,
                       const float* __restrict__ fwx_re, const float* __restrict__ fwx_im,
                       float* __restrict__ ws){
    unsigned int* wm = (unsigned int*)((char*)ws + WSB_WMIX);
    int e = blockIdx.x*256 + threadIdx.x;   // < 524288
    int ax = e >> 18;
    int r  = e & 262143;
    int l  = r >> 16;
    int k  = (r >> 12) & 15;
    int i  = (r >> 6) & 63;
    int o  = r & 63;
    long sidx = (((long)l*64 + i)*64 + o)*16 + k;
    float re = ax ? fwx_re[sidx] : fwy_re[sidx];
    float im = ax ? fwx_im[sidx] : fwy_im[sidx];
    wm[e] = (unsigned int)f2bf(re) | ((unsigned int)f2bf(im) << 16);
}

// ============ input embedding ============
__global__ __launch_bounds__(256) void k_embed(const float* __restrict__ xin,
                                               const float* __restrict__ in_w,
                                               const float* __restrict__ in_b,
                                               float* __restrict__ X){
    long row = (long)blockIdx.x*4 + (threadIdx.x >> 6);
    int d = threadIdx.x & 63;
    const float* xr = xin + row*DIN;
    float acc = in_b[d];
    #pragma unroll
    for (int i = 0; i < DIN; i++) acc += xr[i] * in_w[i*D_ + d];
    X[row*D_ + d] = acc;
}

// ============ K1: fused x-axis spectral conv (fwd+mix+inv), 2 col-slabs/block ====
// LDS: XsT s*16384 (0..32767) | T 32768 + s*4096 | P (post-fwd) s*5120 @0
__global__ __launch_bounds__(256, 4) void k_spec_x(float* __restrict__ ws_f, int layer){
    __shared__ __attribute__((aligned(16))) char lds[40960];
    int t = threadIdx.x, w = t >> 6, lane = t & 63;
    int l15 = lane & 15, l4 = lane >> 4;
    int bb = blockIdx.x >> 6;
    int c  = blockIdx.x & 63;
    const float* X = ws_f;

    // ---- P1: stage XsT (transposed [i][m]) for both slabs ----
    for (int s = 0; s < 2; s++){
        long base = (long)bb*1048576 + (long)(c*2 + s)*64;
        char* xst = lds + s*16384;
        #pragma unroll
        for (int it = 0; it < 4; it++){
            int iq = t & 15, np = (t >> 4) + it*16;
            int i0 = iq*4;
            f32x4 v0 = *(const f32x4*)&X[base + (long)(2*np)*8192 + i0];
            f32x4 v1 = *(const f32x4*)&X[base + (long)(2*np + 1)*8192 + i0];
            #pragma unroll
            for (int j = 0; j < 4; j++){
                int i = i0 + j;
                *(unsigned int*)(xst + i*256 + ((np*4) ^ ((i & 15) << 4))) = cvtpk(v0[j], v1[j]);
            }
        }
    }
    __syncthreads();

    // ---- P2: fwd MFMA (Bf A-frags direct from global) ----
    int mt = w & 1, nt0 = (w >> 1)*2;
    {
        const unsigned short* bfg = (const unsigned short*)((char*)ws_f + WSB_BF);
        int kpr = mt*16 + l15;
        s16x8 bfA[4];
        #pragma unroll
        for (int ks = 0; ks < 4; ks++)
            bfA[ks] = *(const s16x8*)&bfg[kpr*128 + (l4 + ks*4)*8];
        for (int s = 0; s < 2; s++){
            char* xst = lds + s*16384;
            f32x4 acc[2] = {{0.f,0.f,0.f,0.f},{0.f,0.f,0.f,0.f}};
            #pragma unroll
            for (int ks = 0; ks < 4; ks++){
                #pragma unroll
                for (int nf = 0; nf < 2; nf++){
                    int i = (nt0 + nf)*16 + l15;
                    s16x8 b = *(const s16x8*)(xst + i*256 + (((l4*16) + ks*64) ^ ((i & 15) << 4)));
                    acc[nf] = __builtin_amdgcn_mfma_f32_16x16x32_bf16(bfA[ks], b, acc[nf], 0, 0, 0);
                }
            }
            char* Ts = lds + 32768 + s*4096;
            #pragma unroll
            for (int nf = 0; nf < 2; nf++){
                int i = (nt0 + nf)*16 + l15;
                #pragma unroll
                for (int q = 0; q < 4; q++){
                    int kp = mt*16 + l4*4 + q;
                    *(unsigned short*)(Ts + kp*128 + ((i*2) ^ ((kp & 7) << 4))) = f2bf(acc[nf][q]);
                }
            }
        }
    }
    __syncthreads();

    // ---- P3: mix (vector fp32 via float2-pk, both slabs share W) -> P @ s*5120 ----
    {
        int k = t >> 4, og = t & 15;
        const unsigned int* Wg = (const unsigned int*)((char*)ws_f + WSB_WMIX)
                                 + ((long)(4 + layer)*16 + k)*4096;   // axis=1 (fwx)
        const char* T0 = lds + 32768;
        const char* T1 = lds + 36864;
        int rre = 2*k, rim = 2*k + 1;
        f32x2 p0[4], p1[4];
        #pragma unroll
        for (int j = 0; j < 4; j++){ p0[j] = (f32x2){0.f,0.f}; p1[j] = (f32x2){0.f,0.f}; }
        for (int i0 = 0; i0 < 64; i0 += 8){
            s16x8 tr0 = *(const s16x8*)(T0 + rre*128 + ((i0*2) ^ ((rre & 7) << 4)));
            s16x8 ti0 = *(const s16x8*)(T0 + rim*128 + ((i0*2) ^ ((rim & 7) << 4)));
            s16x8 tr1 = *(const s16x8*)(T1 + rre*128 + ((i0*2) ^ ((rre & 7) << 4)));
            s16x8 ti1 = *(const s16x8*)(T1 + rim*128 + ((i0*2) ^ ((rim & 7) << 4)));
            #pragma unroll
            for (int e = 0; e < 8; e++){
                u32x4 wv = *(const u32x4*)&Wg[(i0 + e)*64 + og*4];
                f32x2 a0 = {bf2f((unsigned short)tr0[e]), bf2f((unsigned short)tr0[e])};
                f32x2 b0 = {bf2f((unsigned short)ti0[e]), bf2f((unsigned short)ti0[e])};
                f32x2 a1 = {bf2f((unsigned short)tr1[e]), bf2f((unsigned short)tr1[e])};
                f32x2 b1 = {bf2f((unsigned short)ti1[e]), bf2f((unsigned short)ti1[e])};
                #pragma unroll
                for (int j = 0; j < 4; j++){
                    float wre = __uint_as_float(wv[j] << 16);
                    float wim = __uint_as_float(wv[j] & 0xffff0000u);
                    f32x2 w1v = {wre, wim};
                    f32x2 w2v = {-wim, wre};
                    p0[j] += a0*w1v + b0*w2v;
                    p1[j] += a1*w1v + b1*w2v;
                }
            }
        }
        #pragma unroll
        for (int j = 0; j < 4; j++){
            int o = og*4 + j;
            *(unsigned int*)(lds + o*80 + ((k*4) ^ ((o & 3) << 4)))        = cvtpk(p0[j][0], p0[j][1]);
            *(unsigned int*)(lds + 5120 + o*80 + ((k*4) ^ ((o & 3) << 4))) = cvtpk(p1[j][0], p1[j][1]);
        }
    }
    __syncthreads();

    // ---- P4: inv MFMA (Bi A-frags from global): XSx = Bi @ P, write bf16 ----
    unsigned short* XSx = (unsigned short*)((char*)ws_f + WSB_XSX);
    {
        const unsigned short* big = (const unsigned short*)((char*)ws_f + WSB_BI);
        s16x8 aInv[2];
        #pragma unroll
        for (int mi = 0; mi < 2; mi++){
            int n_ = (w*2 + mi)*16 + l15;
            aInv[mi] = *(const s16x8*)&big[n_*32 + l4*8];
        }
        for (int s = 0; s < 2; s++){
            const char* Ps = lds + s*5120;
            int nc = c*2 + s;
            s16x8 bfr[4];
            #pragma unroll
            for (int nt = 0; nt < 4; nt++){
                int o = nt*16 + l15;
                bfr[nt] = *(const s16x8*)(Ps + o*80 + ((l4*16) ^ ((o & 3) << 4)));
            }
            #pragma unroll
            for (int mi = 0; mi < 2; mi++){
                #pragma unroll
                for (int nt = 0; nt < 4; nt++){
                    f32x4 z = {0.f,0.f,0.f,0.f};
                    f32x4 acc = __builtin_amdgcn_mfma_f32_16x16x32_bf16(aInv[mi], bfr[nt], z, 0, 0, 0);
                    #pragma unroll
                    for (int q = 0; q < 4; q++){
                        int m = (w*2 + mi)*16 + l4*4 + q;
                        int o = nt*16 + l15;
                        XSx[(long)bb*1048576 + (long)m*8192 + nc*64 + o] = f2bf(acc[q]);
                    }
                }
            }
        }
    }
}

// ============ K2: fused y-axis spectral conv + FeedForward block ============
// LDS 48KB: XsT/W @0 (16K) | T @16384 (4K) | P @20480 (5K) | XS @25600 (16K) | H @16384 (32K)
__global__ __launch_bounds__(256, 3) void k_spec_y_ff(
        float* __restrict__ ws_f, float* __restrict__ out,
        const float* __restrict__ bc_b1, const float* __restrict__ bc_b2,
        const float* __restrict__ fc_b1, int layer, int first){
    __shared__ __attribute__((aligned(16))) char lds[49152];
    int t = threadIdx.x, w = t >> 6, lane = t & 63;
    int l15 = lane & 15, l4 = lane >> 4;
    long slab = blockIdx.x;                 // b*128 + m
    float* X = ws_f;
    long xbase = slab*8192;
    const unsigned short* wb = (const unsigned short*)((char*)ws_f + WSB_WFF);

    // ---- P1: stage XsT transposed [i][n] ----
    #pragma unroll
    for (int it = 0; it < 4; it++){
        int iq = t & 15, np = (t >> 4) + it*16;
        int i0 = iq*4;
        f32x4 v0 = *(const f32x4*)&X[xbase + (long)(2*np)*64 + i0];
        f32x4 v1 = *(const f32x4*)&X[xbase + (long)(2*np + 1)*64 + i0];
        #pragma unroll
        for (int j = 0; j < 4; j++){
            int i = i0 + j;
            *(unsigned int*)(lds + i*256 + ((np*4) ^ ((i & 15) << 4))) = cvtpk(v0[j], v1[j]);
        }
    }
    __syncthreads();

    // ---- P2: fwd MFMA (Bf from global) -> T @16384 ----
    int mt = w & 1, nt0 = (w >> 1)*2;
    {
        const unsigned short* bfg = (const unsigned short*)((char*)ws_f + WSB_BF);
        int kpr = mt*16 + l15;
        f32x4 acc[2] = {{0.f,0.f,0.f,0.f},{0.f,0.f,0.f,0.f}};
        #pragma unroll
        for (int ks = 0; ks < 4; ks++){
            s16x8 a = *(const s16x8*)&bfg[kpr*128 + (l4 + ks*4)*8];
            #pragma unroll
            for (int nf = 0; nf < 2; nf++){
                int i = (nt0 + nf)*16 + l15;
                s16x8 b = *(const s16x8*)(lds + i*256 + (((l4*16) + ks*64) ^ ((i & 15) << 4)));
                acc[nf] = __builtin_amdgcn_mfma_f32_16x16x32_bf16(a, b, acc[nf], 0, 0, 0);
            }
        }
        #pragma unroll
        for (int nf = 0; nf < 2; nf++){
            int i = (nt0 + nf)*16 + l15;
            #pragma unroll
            for (int q = 0; q < 4; q++){
                int kp = mt*16 + l4*4 + q;
                *(unsigned short*)(lds + 16384 + kp*128 + ((i*2) ^ ((kp & 7) << 4))) = f2bf(acc[nf][q]);
            }
        }
    }
    __syncthreads();

    // ---- P3: mix (axis=0, fwy) -> P @20480 ----
    {
        int k = t >> 4, og = t & 15;
        const unsigned int* Wg = (const unsigned int*)((char*)ws_f + WSB_WMIX)
                                 + ((long)layer*16 + k)*4096;
        const char* T0 = lds + 16384;
        int rre = 2*k, rim = 2*k + 1;
        f32x2 p[4];
        #pragma unroll
        for (int j = 0; j < 4; j++) p[j] = (f32x2){0.f,0.f};
        for (int i0 = 0; i0 < 64; i0 += 8){
            s16x8 tr = *(const s16x8*)(T0 + rre*128 + ((i0*2) ^ ((rre & 7) << 4)));
            s16x8 ti = *(const s16x8*)(T0 + rim*128 + ((i0*2) ^ ((rim & 7) << 4)));
            #pragma unroll
            for (int e = 0; e < 8; e++){
                u32x4 wv = *(const u32x4*)&Wg[(i0 + e)*64 + og*4];
                f32x2 av = {bf2f((unsigned short)tr[e]), bf2f((unsigned short)tr[e])};
                f32x2 bv = {bf2f((unsigned short)ti[e]), bf2f((unsigned short)ti[e])};
                #pragma unroll
                for (int j = 0; j < 4; j++){
                    float wre = __uint_as_float(wv[j] << 16);
                    float wim = __uint_as_float(wv[j] & 0xffff0000u);
                    f32x2 w1v = {wre, wim};
                    f32x2 w2v = {-wim, wre};
                    p[j] += av*w1v + bv*w2v;
                }
            }
        }
        #pragma unroll
        for (int j = 0; j < 4; j++){
            int o = og*4 + j;
            *(unsigned int*)(lds + 20480 + o*80 + ((k*4) ^ ((o & 3) << 4))) = cvtpk(p[j][0], p[j][1]);
        }
    }
    __syncthreads();

    // ---- P4: inv MFMA (Bi from global) + XSx add -> XS bf16 @25600 ----
    {
        const unsigned short* big = (const unsigned short*)((char*)ws_f + WSB_BI);
        const unsigned short* XSxg = (const unsigned short*)((char*)ws_f + WSB_XSX) + slab*8192;
        s16x8 bfr[4];
        #pragma unroll
        for (int nt = 0; nt < 4; nt++){
            int o = nt*16 + l15;
            bfr[nt] = *(const s16x8*)(lds + 20480 + o*80 + ((l4*16) ^ ((o & 3) << 4)));
        }
        #pragma unroll
        for (int mi = 0; mi < 2; mi++){
            int n_ = (w*2 + mi)*16 + l15;
            s16x8 a = *(const s16x8*)&big[n_*32 + l4*8];
            #pragma unroll
            for (int nt = 0; nt < 4; nt++){
                f32x4 z = {0.f,0.f,0.f,0.f};
                f32x4 acc = __builtin_amdgcn_mfma_f32_16x16x32_bf16(a, bfr[nt], z, 0, 0, 0);
                #pragma unroll
                for (int q = 0; q < 4; q++){
                    int nr = (w*2 + mi)*16 + l4*4 + q;
                    int o = nt*16 + l15;
                    float v = acc[q] + bf2f(XSxg[nr*64 + o]);
                    *(unsigned short*)(lds + 25600 + nr*128 + ((o*2) ^ ((nr & 7) << 4))) = f2bf(v);
                }
            }
        }
    }
    __syncthreads();

    // ---- P5: load XS A-frags to regs (shared by GEMM1/GEMM3) + stage bc_w1 @0 ----
    s16x8 af[2][2];
    #pragma unroll
    for (int rr = 0; rr < 2; rr++)
    #pragma unroll
    for (int ks = 0; ks < 2; ks++){
        int r = w*32 + rr*16 + l15, kch = l4 + ks*4;
        af[rr][ks] = *(const s16x8*)(lds + 25600 + r*128 + ((kch << 4) ^ ((r & 7) << 4)));
    }
    {
        const u32x4* src = (const u32x4*)(wb + (long)layer*8192);
        for (int cq = t; cq < 1024; cq += 256){
            int r = cq >> 3, c8 = cq & 7;
            *(u32x4*)(lds + r*128 + ((c8 << 4) ^ ((r & 7) << 4))) = src[cq];
        }
    }
    __syncthreads();

    // ---- P6: GEMM1 (bc): h = relu(xs@w1+b1) -> H @16384 ----
    {
        f32x4 acc[2][8];
        #pragma unroll
        for (int mi = 0; mi < 2; mi++)
        #pragma unroll
        for (int nf = 0; nf < 8; nf++) acc[mi][nf] = (f32x4){0.f,0.f,0.f,0.f};
        #pragma unroll
        for (int ks = 0; ks < 2; ks++){
            int kch = l4 + ks*4;
            #pragma unroll
            for (int nf = 0; nf < 8; nf++){
                int n = nf*16 + l15;
                s16x8 b = *(const s16x8*)(lds + n*128 + ((kch << 4) ^ ((n & 7) << 4)));
                acc[0][nf] = __builtin_amdgcn_mfma_f32_16x16x32_bf16(af[0][ks], b, acc[0][nf], 0, 0, 0);
                acc[1][nf] = __builtin_amdgcn_mfma_f32_16x16x32_bf16(af[1][ks], b, acc[1][nf], 0, 0, 0);
            }
        }
        #pragma unroll
        for (int mi = 0; mi < 2; mi++)
        #pragma unroll
        for (int nf = 0; nf < 8; nf++){
            int ncol = nf*16 + l15;
            float b1 = bc_b1[layer*128 + ncol];
            #pragma unroll
            for (int q = 0; q < 4; q++){
                int mrow = w*32 + mi*16 + l4*4 + q;
                float hv = fmaxf(acc[mi][nf][q] + b1, 0.f);
                *(unsigned short*)(lds + 16384 + mrow*256 + (((ncol >> 3) << 4) ^ ((mrow & 7) << 4)) + (ncol & 7)*2) = f2bf(hv);
            }
        }
    }
    __syncthreads();
    // ---- P7: stage bc_w2T [64][128] @0 ----
    {
        const u32x4* src = (const u32x4*)(wb + 65536 + (long)layer*8192);
        for (int cq = t; cq < 1024; cq += 256){
            int r = cq >> 4, c16 = cq & 15;
            *(u32x4*)(lds + r*256 + ((c16 << 4) ^ ((r & 7) << 4))) = src[cq];
        }
    }
    __syncthreads();
    // ---- P8: GEMM2: X = X - (h@w2+b2) ----
    {
        f32x4 acc[2][4];
        #pragma unroll
        for (int mi = 0; mi < 2; mi++)
        #pragma unroll
        for (int nf = 0; nf < 4; nf++) acc[mi][nf] = (f32x4){0.f,0.f,0.f,0.f};
        #pragma unroll
        for (int ks = 0; ks < 4; ks++){
            int kch = l4 + ks*4;
            int r0 = w*32 + l15, r1 = w*32 + 16 + l15;
            s16x8 a0 = *(const s16x8*)(lds + 16384 + r0*256 + ((kch << 4) ^ ((r0 & 7) << 4)));
            s16x8 a1 = *(const s16x8*)(lds + 16384 + r1*256 + ((kch << 4) ^ ((r1 & 7) << 4)));
            #pragma unroll
            for (int nf = 0; nf < 4; nf++){
                int n = nf*16 + l15;
                s16x8 b = *(const s16x8*)(lds + n*256 + ((kch << 4) ^ ((n & 7) << 4)));
                acc[0][nf] = __builtin_amdgcn_mfma_f32_16x16x32_bf16(a0, b, acc[0][nf], 0, 0, 0);
                acc[1][nf] = __builtin_amdgcn_mfma_f32_16x16x32_bf16(a1, b, acc[1][nf], 0, 0, 0);
            }
        }
        #pragma unroll
        for (int mi = 0; mi < 2; mi++)
        #pragma unroll
        for (int nf = 0; nf < 4; nf++){
            int ncol = nf*16 + l15;
            float b2 = bc_b2[layer*64 + ncol];
            #pragma unroll
            for (int q = 0; q < 4; q++){
                int mrow = w*32 + mi*16 + l4*4 + q;
                long g = xbase + (long)mrow*64 + ncol;
                X[g] = X[g] - (acc[mi][nf][q] + b2);
            }
        }
    }
    __syncthreads();
    // ---- P9: stage fc_w1T @0 ; load head vectors ----
    {
        const u32x4* src = (const u32x4*)(wb + 32768 + (long)layer*8192);
        for (int cq = t; cq < 1024; cq += 256){
            int r = cq >> 3, c8 = cq & 7;
            *(u32x4*)(lds + r*128 + ((c8 << 4) ^ ((r & 7) << 4))) = src[cq];
        }
    }
    float uv[8], b1v[8];
    {
        const float* up = (const float*)((char*)ws_f + WSB_U) + layer*128;
        #pragma unroll
        for (int nf = 0; nf < 8; nf++){
            uv[nf]  = up[nf*16 + l15];
            b1v[nf] = fc_b1[layer*128 + nf*16 + l15];
        }
    }
    float ddv = *((const float*)((char*)ws_f + WSB_D) + layer);
    __syncthreads();
    // ---- P10: GEMM3 (fc) + head from accumulators ----
    {
        f32x4 acc[2][8];
        #pragma unroll
        for (int mi = 0; mi < 2; mi++)
        #pragma unroll
        for (int nf = 0; nf < 8; nf++) acc[mi][nf] = (f32x4){0.f,0.f,0.f,0.f};
        #pragma unroll
        for (int ks = 0; ks < 2; ks++){
            int kch = l4 + ks*4;
            #pragma unroll
            for (int nf = 0; nf < 8; nf++){
                int n = nf*16 + l15;
                s16x8 b = *(const s16x8*)(lds + n*128 + ((kch << 4) ^ ((n & 7) << 4)));
                acc[0][nf] = __builtin_amdgcn_mfma_f32_16x16x32_bf16(af[0][ks], b, acc[0][nf], 0, 0, 0);
                acc[1][nf] = __builtin_amdgcn_mfma_f32_16x16x32_bf16(af[1][ks], b, acc[1][nf], 0, 0, 0);
            }
        }
        #pragma unroll
        for (int mi = 0; mi < 2; mi++)
        #pragma unroll
        for (int q = 0; q < 4; q++){
            float s = 0.f;
            #pragma unroll
            for (int nf = 0; nf < 8; nf++)
                s += fmaxf(acc[mi][nf][q] + b1v[nf], 0.f) * uv[nf];
            s += __shfl_xor(s, 1);
            s += __shfl_xor(s, 2);
            s += __shfl_xor(s, 4);
            s += __shfl_xor(s, 8);
            if (l15 == 0){
                int r = w*32 + mi*16 + l4*4 + q;
                long g = slab*128 + r;
                float fo = s + ddv;
                out[g] = first ? fo : (out[g] + fo);
            }
        }
    }
}

// ============ host launch ============
extern "C" void kernel_launch(void* const* d_in, const int* in_sizes, int n_in,
                              void* d_out, int out_size, void* d_ws, size_t ws_size,
                              hipStream_t stream){
    if (ws_size < (size_t)WS_NEEDED) return;
    const float* xin    = (const float*)d_in[0];
    const float* in_w   = (const float*)d_in[1];
    const float* in_b   = (const float*)d_in[2];
    const float* fwy_re = (const float*)d_in[3];
    const float* fwy_im = (const float*)d_in[4];
    const float* fwx_re = (const float*)d_in[5];
    const float* fwx_im = (const float*)d_in[6];
    const float* bc_w1  = (const float*)d_in[7];
    const float* bc_b1  = (const float*)d_in[8];
    const float* bc_w2  = (const float*)d_in[9];
    const float* bc_b2  = (const float*)d_in[10];
    const float* fc_w1  = (const float*)d_in[11];
    const float* fc_b1  = (const float*)d_in[12];
    const float* fc_w2  = (const float*)d_in[13];
    const float* fc_b2  = (const float*)d_in[14];
    const float* out_w1 = (const float*)d_in[15];
    const float* out_b1 = (const float*)d_in[16];
    const float* out_w2 = (const float*)d_in[17];
    const float* out_b2 = (const float*)d_in[18];
    float* ws  = (float*)d_ws;
    float* out = (float*)d_out;

    k_init<<<1, 256, 0, stream>>>(out_w1, out_b1, out_w2, out_b2, fc_w2, fc_b2, ws);
    k_wconv<<<384, 256, 0, stream>>>(bc_w1, fc_w1, bc_w2, ws);
    k_wmix<<<2048, 256, 0, stream>>>(fwy_re, fwy_im, fwx_re, fwx_im, ws);
    k_embed<<<NPIX/4, 256, 0, stream>>>(xin, in_w, in_b, ws);

    for (int l = 0; l < NL; l++){
        k_spec_x<<<1024, 256, 0, stream>>>(ws, l);
        k_spec_y_ff<<<2048, 256, 0, stream>>>(ws, out, bc_b1, bc_b2, fc_b1, l, l == 0 ? 1 : 0);
    }
}